// Round 3
// baseline (582.882 us; speedup 1.0000x reference)
//
#include <hip/hip_runtime.h>
#include <hip/hip_bf16.h>

#define N 8192
#define D 128
#define INV_T 14.285714285714286f   // 1/0.07
#define LDS_PITCH 136               // bf16 elems; 272 B row stride breaks bank alignment

typedef __bf16 v8bf __attribute__((ext_vector_type(8)));
typedef __bf16 v4bf __attribute__((ext_vector_type(4)));
typedef float  v4f  __attribute__((ext_vector_type(4)));

// ---------------- Kernel 1: row-normalize fp32 -> bf16 ----------------
__global__ __launch_bounds__(256) void normalize_kernel(
    const float* __restrict__ f, __bf16* __restrict__ out)
{
    int gwave = (blockIdx.x * blockDim.x + threadIdx.x) >> 6;  // row id
    int lane  = threadIdx.x & 63;
    const float2 v = *reinterpret_cast<const float2*>(f + (size_t)gwave * D + lane * 2);
    float ss = v.x * v.x + v.y * v.y;
    #pragma unroll
    for (int m = 32; m; m >>= 1) ss += __shfl_xor(ss, m);
    float inv = 1.0f / fmaxf(sqrtf(ss), 1e-8f);
    __bf16* o = out + (size_t)gwave * D + lane * 2;
    o[0] = (__bf16)(v.x * inv);
    o[1] = (__bf16)(v.y * inv);
}

// ---------------- Kernel 2: Gram tile -> exp -> LDS -> coalesced masked reduce --------
__global__ __launch_bounds__(256) void supcon_main(
    const __bf16* __restrict__ F,
    const int* __restrict__ pmask, const int* __restrict__ nmask,
    float* __restrict__ pos, float* __restrict__ neg)
{
    __shared__ __bf16 E[128 * LDS_PITCH];   // 34816 B

    const int tid  = threadIdx.x;
    const int lane = tid & 63;
    const int wid  = tid >> 6;       // 0..3
    const int wr   = wid >> 1, wc = wid & 1;
    const int i0   = blockIdx.y * 128;
    const int j0   = blockIdx.x * 128;
    const int iw   = i0 + wr * 64;
    const int jw   = j0 + wc * 64;
    const int r    = lane & 15;
    const int q    = lane >> 4;      // 0..3

    v4f acc[4][4];
    #pragma unroll
    for (int m = 0; m < 4; ++m)
        #pragma unroll
        for (int n = 0; n < 4; ++n) acc[m][n] = (v4f)0.0f;

    // ---- MFMA: K = 128 in 4 steps of 32 (fragments straight from global; F is L2-resident)
    #pragma unroll
    for (int ks = 0; ks < 4; ++ks) {
        v8bf a[4], b[4];
        #pragma unroll
        for (int m = 0; m < 4; ++m)
            a[m] = *reinterpret_cast<const v8bf*>(F + (size_t)(iw + m * 16 + r) * D + ks * 32 + q * 8);
        #pragma unroll
        for (int n = 0; n < 4; ++n)
            b[n] = *reinterpret_cast<const v8bf*>(F + (size_t)(jw + n * 16 + r) * D + ks * 32 + q * 8);
        #pragma unroll
        for (int m = 0; m < 4; ++m)
            #pragma unroll
            for (int n = 0; n < 4; ++n)
                acc[m][n] = __builtin_amdgcn_mfma_f32_16x16x32_bf16(a[m], b[n], acc[m][n], 0, 0, 0);
    }

    // ---- exp + diagonal kill + bf16 store to LDS
    const bool diag = (blockIdx.x == blockIdx.y);
    #pragma unroll
    for (int m = 0; m < 4; ++m) {
        #pragma unroll
        for (int n = 0; n < 4; ++n) {
            const int colL = wc * 64 + n * 16 + r;
            #pragma unroll
            for (int v = 0; v < 4; ++v) {
                const int rowL = wr * 64 + m * 16 + q * 4 + v;
                float e = __expf(acc[m][n][v] * INV_T);
                if (diag && rowL == colL) e = 0.0f;
                E[rowL * LDS_PITCH + colL] = (__bf16)e;
            }
        }
    }
    __syncthreads();

    // ---- reduce: wave owns 32 rows; 2 rows/iter (half-wave each); int4 mask loads
    const int half = lane >> 5;      // 0/1 -> which of the 2 rows
    const int c    = lane & 31;      // col chunk: cols 4c..4c+3
    #pragma unroll
    for (int it = 0; it < 16; ++it) {
        const int row = wid * 32 + it * 2 + half;
        const int gi  = i0 + row;
        const size_t base = (size_t)gi * N + j0 + c * 4;
        const int4 pm = *reinterpret_cast<const int4*>(pmask + base);
        const int4 nm = *reinterpret_cast<const int4*>(nmask + base);
        const v4bf ev = *reinterpret_cast<const v4bf*>(&E[row * LDS_PITCH + c * 4]);
        const float e0 = (float)ev[0], e1 = (float)ev[1];
        const float e2 = (float)ev[2], e3 = (float)ev[3];
        float p = fmaf((float)pm.x, e0, fmaf((float)pm.y, e1,
                  fmaf((float)pm.z, e2, (float)pm.w * e3)));
        float g = fmaf((float)nm.x, e0, fmaf((float)nm.y, e1,
                  fmaf((float)nm.z, e2, (float)nm.w * e3)));
        #pragma unroll
        for (int msk = 1; msk < 32; msk <<= 1) {   // stays within each 32-lane half
            p += __shfl_xor(p, msk);
            g += __shfl_xor(g, msk);
        }
        if (c == 0) {
            atomicAdd(&pos[gi], p);
            atomicAdd(&neg[gi], g);
        }
    }
}

// ---------------- Kernel 3: loss = -mean(log(pos/(pos+neg))) ----------------
__global__ __launch_bounds__(1024) void finalize_kernel(
    const float* __restrict__ pos, const float* __restrict__ neg, float* __restrict__ out)
{
    __shared__ float sm[16];
    int tid = threadIdx.x;
    float acc = 0.0f;
    for (int i = tid; i < N; i += 1024) {
        float p = pos[i], g = neg[i];
        acc += logf(p / (p + g));
    }
    #pragma unroll
    for (int m = 32; m; m >>= 1) acc += __shfl_xor(acc, m);
    if ((tid & 63) == 0) sm[tid >> 6] = acc;
    __syncthreads();
    if (tid == 0) {
        float t = 0.0f;
        #pragma unroll
        for (int w = 0; w < 16; ++w) t += sm[w];
        out[0] = -t * (1.0f / (float)N);
    }
}

extern "C" void kernel_launch(void* const* d_in, const int* in_sizes, int n_in,
                              void* d_out, int out_size, void* d_ws, size_t ws_size,
                              hipStream_t stream) {
    const float* feat  = (const float*)d_in[0];
    const int*   pmask = (const int*)d_in[1];
    const int*   nmask = (const int*)d_in[2];
    float* out = (float*)d_out;

    char* ws = (char*)d_ws;
    __bf16* fnb = (__bf16*)ws;                              // 2 MB
    float*  pos = (float*)(ws + (size_t)2 * 1024 * 1024);
    float*  neg = pos + N;

    hipMemsetAsync(pos, 0, 2 * N * sizeof(float), stream);

    normalize_kernel<<<dim3(N / 4), 256, 0, stream>>>(feat, fnb);

    dim3 grid(N / 128, N / 128);
    supcon_main<<<grid, 256, 0, stream>>>(fnb, pmask, nmask, pos, neg);

    finalize_kernel<<<1, 1024, 0, stream>>>(pos, neg, out);
}